// Round 2
// baseline (3134.711 us; speedup 1.0000x reference)
//
#include <hip/hip_runtime.h>
#include <math.h>

#define V 64
#define TMAX 2048
#define ED 512
#define H 64
#define G3 192
#define TT 128
#define KCH 32

// ---------------- K0: zero the persistent hidden state ----------------
__global__ void k_init(float* __restrict__ h) {
    int i = blockIdx.x * blockDim.x + threadIdx.x;
    if (i < V * H) h[i] = 0.f;
}

// ---------------- K1: xg[v, tloc, g] = b_ih[g] + sum_k emb[v,t,k] * W_ih[g,k]
// Block tile 128t x 192g, thread tile 8t x 12g, K chunk 32.
// LDS rows stride 36 floats; element (row,k) stored at col (k + 4*(row/blk)) & 31
// so per-k4 reads hit <=2-way banks (free) and broadcast across the other dim.
__global__ __launch_bounds__(256) void k_gemm(
    const float* __restrict__ emb, const int* __restrict__ lengths,
    const float* __restrict__ W_ih, const float* __restrict__ b_ih,
    float* __restrict__ xg, int c, int CT) {
    int v = blockIdx.y;
    int tile0 = blockIdx.x * TT;        // local t within CT chunk
    int t0abs = c * CT + tile0;         // absolute t
    if (t0abs >= lengths[v]) return;    // tile never read downstream

    __shared__ __align__(16) float Es[TT][36];
    __shared__ __align__(16) float Ws[G3][36];

    int th = threadIdx.x;
    int tq = th & 15;       // t-group: rows tq*8 .. tq*8+7
    int gq = th >> 4;       // g-group: rows gq*12 .. gq*12+11
    int kq = th & 7;        // staging: k quad
    int rowq = th >> 3;     // staging: row within 32-row pass

    float acc[8][12];
#pragma unroll
    for (int i = 0; i < 8; i++)
#pragma unroll
        for (int j = 0; j < 12; j++) acc[i][j] = 0.f;

    const float* ebase = emb + ((size_t)v * TMAX + t0abs) * ED;

    for (int kc = 0; kc < ED; kc += KCH) {
        // stage E tile: 128 rows x 32 k
#pragma unroll
        for (int p = 0; p < 4; p++) {
            int t = p * 32 + rowq;
            float4 val = *(const float4*)&ebase[(size_t)t * ED + kc + kq * 4];
            int pos = (kq * 4 + 4 * (t >> 3)) & 31;
            *(float4*)&Es[t][pos] = val;
        }
        // stage W tile: 192 rows x 32 k
#pragma unroll
        for (int p = 0; p < 6; p++) {
            int g = p * 32 + rowq;
            float4 val = *(const float4*)&W_ih[(size_t)g * ED + kc + kq * 4];
            int pos = (kq * 4 + 4 * (g / 12)) & 31;
            *(float4*)&Ws[g][pos] = val;
        }
        __syncthreads();
#pragma unroll
        for (int k4 = 0; k4 < 8; k4++) {
            int epos = (k4 * 4 + 4 * tq) & 31;
            int wpos = (k4 * 4 + 4 * gq) & 31;
            float4 e[8], w[12];
#pragma unroll
            for (int i = 0; i < 8; i++) e[i] = *(float4*)&Es[tq * 8 + i][epos];
#pragma unroll
            for (int j = 0; j < 12; j++) w[j] = *(float4*)&Ws[gq * 12 + j][wpos];
#pragma unroll
            for (int i = 0; i < 8; i++)
#pragma unroll
                for (int j = 0; j < 12; j++)
                    acc[i][j] += e[i].x * w[j].x + e[i].y * w[j].y +
                                 e[i].z * w[j].z + e[i].w * w[j].w;
        }
        __syncthreads();
    }

    // epilogue: add bias, store
#pragma unroll
    for (int i = 0; i < 8; i++) {
        int tloc = tile0 + tq * 8 + i;
        size_t ob = ((size_t)v * CT + tloc) * G3 + gq * 12;
#pragma unroll
        for (int j4 = 0; j4 < 3; j4++) {
            float4 o;
            o.x = acc[i][j4 * 4 + 0] + b_ih[gq * 12 + j4 * 4 + 0];
            o.y = acc[i][j4 * 4 + 1] + b_ih[gq * 12 + j4 * 4 + 1];
            o.z = acc[i][j4 * 4 + 2] + b_ih[gq * 12 + j4 * 4 + 2];
            o.w = acc[i][j4 * 4 + 3] + b_ih[gq * 12 + j4 * 4 + 3];
            *(float4*)&xg[ob + j4 * 4] = o;
        }
    }
}

// ---------------- K2: sequential GRU recurrence, one block (3 waves) per var.
// wave0 = r rows + state update, wave1 = z rows (applies sigmoid), wave2 = n rows.
// xg staged through double-buffered LDS in 8-step chunks, loads 8 steps ahead.
__global__ __launch_bounds__(192) void k_rec(
    const float* __restrict__ xg, const int* __restrict__ lengths,
    const float* __restrict__ W_hh, const float* __restrict__ b_hh,
    float* __restrict__ h, int c, int CT) {
    int v = blockIdx.x;
    int th = threadIdx.x;
    int len = lengths[v];
    int rem = len - c * CT;
    int tcnt = rem < 0 ? 0 : (rem > CT ? CT : rem);

    __shared__ __align__(16) float hs[H];
    __shared__ float gbuf[128];
    __shared__ __align__(16) float xb[2][8 * G3];

    float4 w4[16];
#pragma unroll
    for (int k4 = 0; k4 < 16; k4++)
        w4[k4] = *(const float4*)&W_hh[(size_t)th * H + k4 * 4];
    float bhh = b_hh[th];

    float hp = 0.f;
    if (th < H) { hp = h[v * H + th]; hs[th] = hp; }

    const float* xgv = xg + (size_t)v * CT * G3;
    float4 p0, p1;
    p0.x = p0.y = p0.z = p0.w = 0.f; p1 = p0;
    if (tcnt > 0) {
        float4 a = *(const float4*)&xgv[th * 8];
        float4 b = *(const float4*)&xgv[th * 8 + 4];
        *(float4*)&xb[0][th * 8] = a;
        *(float4*)&xb[0][th * 8 + 4] = b;
        if (tcnt > 8) {
            p0 = *(const float4*)&xgv[1536 + th * 8];
            p1 = *(const float4*)&xgv[1536 + th * 8 + 4];
        }
    }
    __syncthreads();

    const float LOG2E = 1.4426950408889634f;

    for (int t = 0; t < tcnt; t++) {
        int tm = t & 7;
        if (tm == 0 && t) {
            // publish chunk t/8 (loaded 8 steps ago), start loading chunk t/8+1
            int bsel = (t >> 3) & 1;
            *(float4*)&xb[bsel][th * 8] = p0;
            *(float4*)&xb[bsel][th * 8 + 4] = p1;
            if (t + 8 < tcnt) {
                p0 = *(const float4*)&xgv[(size_t)(t + 8) * G3 + th * 8];
                p1 = *(const float4*)&xgv[(size_t)(t + 8) * G3 + th * 8 + 4];
            }
            __syncthreads();
        }
        int bsel = (t >> 3) & 1;

        // matvec: hg = W_hh[th,:] . h  (4 independent chains)
        float a0 = 0.f, a1 = 0.f, a2 = 0.f, a3 = 0.f;
#pragma unroll
        for (int k4 = 0; k4 < 16; k4 += 4) {
            float4 h0 = *(float4*)&hs[k4 * 4];
            float4 h1 = *(float4*)&hs[k4 * 4 + 4];
            float4 h2 = *(float4*)&hs[k4 * 4 + 8];
            float4 h3 = *(float4*)&hs[k4 * 4 + 12];
            a0 += w4[k4].x * h0.x + w4[k4].y * h0.y + w4[k4].z * h0.z + w4[k4].w * h0.w;
            a1 += w4[k4 + 1].x * h1.x + w4[k4 + 1].y * h1.y + w4[k4 + 1].z * h1.z + w4[k4 + 1].w * h1.w;
            a2 += w4[k4 + 2].x * h2.x + w4[k4 + 2].y * h2.y + w4[k4 + 2].z * h2.z + w4[k4 + 2].w * h2.w;
            a3 += w4[k4 + 3].x * h3.x + w4[k4 + 3].y * h3.y + w4[k4 + 3].z * h3.z + w4[k4 + 3].w * h3.w;
        }
        float hg = ((a0 + a1) + (a2 + a3)) + bhh;

        float rr = 0.f;
        if (th >= 128) {
            gbuf[64 + (th - 128)] = hg;            // raw hn
        } else if (th >= 64) {
            float xz = xb[bsel][tm * G3 + th];     // == tm*192 + 64 + (th-64)
            gbuf[th - 64] = __builtin_amdgcn_rcpf(
                1.f + __builtin_amdgcn_exp2f(-LOG2E * (hg + xz)));
        } else {
            float xr = xb[bsel][tm * G3 + th];
            rr = __builtin_amdgcn_rcpf(
                1.f + __builtin_amdgcn_exp2f(-LOG2E * (hg + xr)));
        }
        __syncthreads();
        if (th < 64) {
            float z  = gbuf[th];
            float hn = gbuf[64 + th];
            float xn = xb[bsel][tm * G3 + 128 + th];
            float arg = xn + rr * hn;
            float e2 = __builtin_amdgcn_exp2f(-2.f * LOG2E * fabsf(arg));
            float tn = (1.f - e2) * __builtin_amdgcn_rcpf(1.f + e2);
            tn = __builtin_copysignf(tn, arg);
            hp = tn + z * (hp - tn);
            hs[th] = hp;
        }
        __syncthreads();
    }
    if (th < H) h[v * H + th] = hp;
}

// ---------------- K2F: fully-fused fallback (tiny workspace). Slow but correct.
__global__ __launch_bounds__(192) void k_rec_fused(
    const float* __restrict__ emb, const int* __restrict__ lengths,
    const float* __restrict__ W_ih, const float* __restrict__ b_ih,
    const float* __restrict__ W_hh, const float* __restrict__ b_hh,
    float* __restrict__ h) {
    int v = blockIdx.x;
    int th = threadIdx.x;
    int len = lengths[v];

    __shared__ __align__(16) float hs[H];
    __shared__ __align__(16) float es[ED];
    __shared__ float znbuf[128];
    __shared__ float xnbuf[64];

    float4 w4[16];
#pragma unroll
    for (int k4 = 0; k4 < 16; k4++)
        w4[k4] = *(const float4*)&W_hh[(size_t)th * H + k4 * 4];
    float bhh = b_hh[th];
    float bih = b_ih[th];
    if (th < H) hs[th] = 0.f;
    const float* ev = emb + (size_t)v * TMAX * ED;
    const float* wrow = W_ih + (size_t)th * ED;

    for (int t = 0; t < len; t++) {
        __syncthreads();
        for (int i = th; i < 128; i += 192)
            *(float4*)&es[i * 4] = *(const float4*)&ev[(size_t)t * ED + i * 4];
        __syncthreads();
        float xgt = bih;
        for (int k4 = 0; k4 < 128; k4++) {
            float4 wv = *(const float4*)&wrow[k4 * 4];
            float4 e4 = *(float4*)&es[k4 * 4];
            xgt += wv.x * e4.x + wv.y * e4.y + wv.z * e4.z + wv.w * e4.w;
        }
        float hg = bhh;
#pragma unroll
        for (int k4 = 0; k4 < 16; k4++) {
            float4 h4 = *(float4*)&hs[k4 * 4];
            hg += w4[k4].x * h4.x + w4[k4].y * h4.y + w4[k4].z * h4.z + w4[k4].w * h4.w;
        }
        if (th >= H && th < 128) znbuf[th - H] = hg + xgt;
        if (th >= 128) { znbuf[th - H] = hg; xnbuf[th - 128] = xgt; }
        __syncthreads();
        if (th < H) {
            float r = 1.f / (1.f + expf(-(hg + xgt)));
            float z = 1.f / (1.f + expf(-znbuf[th]));
            float n = tanhf(xnbuf[th] + r * znbuf[64 + th]);
            float hold = hs[th];
            hs[th] = (1.f - z) * n + z * hold;
        }
    }
    __syncthreads();
    if (th < H) h[v * H + th] = hs[th];
}

// ---------------- K3a: hid[o] = relu(b1[o] + W1[o,:] . concat)
__global__ __launch_bounds__(256) void k_mlp1(
    const float* __restrict__ h, const float* __restrict__ W1,
    const float* __restrict__ b1, float* __restrict__ hid) {
    int o = blockIdx.x, th = threadIdx.x;
    const float* w = W1 + (size_t)o * (V * H);
    float s = 0.f;
#pragma unroll
    for (int r = 0; r < 4; r++) {
        int i = (th + r * 256) * 4;
        float4 a = *(const float4*)&w[i];
        float4 b = *(const float4*)&h[i];
        s += a.x * b.x + a.y * b.y + a.z * b.z + a.w * b.w;
    }
    __shared__ float red[4];
    for (int off = 32; off; off >>= 1) s += __shfl_down(s, off);
    if ((th & 63) == 0) red[th >> 6] = s;
    __syncthreads();
    if (th == 0) {
        float tot = red[0] + red[1] + red[2] + red[3] + b1[o];
        hid[o] = tot > 0.f ? tot : 0.f;
    }
}

// ---------------- K3b: out = b2 + W2 . hid
__global__ void k_mlp2(const float* __restrict__ hid, const float* __restrict__ W2,
                       const float* __restrict__ b2, float* __restrict__ out) {
    int th = threadIdx.x;
    float s = hid[th] * W2[th];
    for (int off = 32; off; off >>= 1) s += __shfl_down(s, off);
    if (th == 0) out[0] = s + b2[0];
}

extern "C" void kernel_launch(void* const* d_in, const int* in_sizes, int n_in,
                              void* d_out, int out_size, void* d_ws, size_t ws_size,
                              hipStream_t stream) {
    const float* emb     = (const float*)d_in[0];
    const int*   lengths = (const int*)d_in[1];
    const float* W_ih    = (const float*)d_in[2];
    const float* W_hh    = (const float*)d_in[3];
    const float* b_ih    = (const float*)d_in[4];
    const float* b_hh    = (const float*)d_in[5];
    const float* W1      = (const float*)d_in[6];
    const float* b1      = (const float*)d_in[7];
    const float* W2      = (const float*)d_in[8];
    const float* b2      = (const float*)d_in[9];
    float* out = (float*)d_out;
    float* wsf = (float*)d_ws;

    const size_t tail = (size_t)V * H + V;  // h + hid (floats)
    int CT = 0;
    const int cts[5] = {2048, 1024, 512, 256, 128};
    for (int i = 0; i < 5; i++) {
        size_t need = ((size_t)V * cts[i] * G3 + tail) * sizeof(float);
        if (need <= ws_size) { CT = cts[i]; break; }
    }

    if (CT > 0) {
        float* xg  = wsf;
        float* hbf = wsf + (size_t)V * CT * G3;
        float* hid = hbf + (size_t)V * H;
        k_init<<<dim3((V * H + 255) / 256), dim3(256), 0, stream>>>(hbf);
        int nch = TMAX / CT;
        for (int c = 0; c < nch; c++) {
            k_gemm<<<dim3(CT / TT, V), dim3(256), 0, stream>>>(emb, lengths, W_ih, b_ih, xg, c, CT);
            k_rec<<<dim3(V), dim3(G3), 0, stream>>>(xg, lengths, W_hh, b_hh, hbf, c, CT);
        }
        k_mlp1<<<dim3(V), dim3(256), 0, stream>>>(hbf, W1, b1, hid);
        k_mlp2<<<dim3(1), dim3(64), 0, stream>>>(hid, W2, b2, out);
    } else {
        float* hbf = wsf;
        float* hid = hbf + (size_t)V * H;
        k_rec_fused<<<dim3(V), dim3(G3), 0, stream>>>(emb, lengths, W_ih, b_ih, W_hh, b_hh, hbf);
        k_mlp1<<<dim3(V), dim3(256), 0, stream>>>(hbf, W1, b1, hid);
        k_mlp2<<<dim3(1), dim3(64), 0, stream>>>(hid, W2, b2, out);
    }
}